// Round 1
// baseline (2787.165 us; speedup 1.0000x reference)
//
#include <hip/hip_runtime.h>
#include <math.h>

// Problem constants (verified against in_sizes at launch where cheap)
#define T_STEPS 8
#define F_IN    8
#define HID     32
#define KCH     5
#define PERIODS 8

__device__ __forceinline__ float sigmoidf_(float x) { return 1.f / (1.f + __expf(-x)); }

// ---------------- graph setup ----------------

// deg (float, by src) for normalization; cnt (int, by dst) for CSR build
__global__ void k_count(const int* __restrict__ src, const int* __restrict__ dst,
                        float* __restrict__ deg, int* __restrict__ cnt, int E) {
    int e = blockIdx.x * blockDim.x + threadIdx.x;
    if (e >= E) return;
    int s = src[e], d = dst[e];
    if (s != d) {
        atomicAdd(&deg[s], 1.f);
        atomicAdd(&cnt[d], 1);
    }
}

__global__ void k_dis(const float* __restrict__ deg, float* __restrict__ dis, int N) {
    int n = blockIdx.x * blockDim.x + threadIdx.x;
    if (n >= N) return;
    float d = deg[n];
    dis[n] = (d > 0.f) ? rsqrtf(d) : 0.f;
}

// exclusive scan of cnt[0..N) -> row_ptr[0..N], single block of 1024 threads
__global__ void __launch_bounds__(1024) k_scan(const int* __restrict__ cnt,
                                               int* __restrict__ row_ptr, int N) {
    __shared__ int buf[1024];
    __shared__ int carry;
    int tid = threadIdx.x;
    if (tid == 0) carry = 0;
    __syncthreads();
    for (int base = 0; base < N; base += 1024) {
        int i = base + tid;
        int v = (i < N) ? cnt[i] : 0;
        buf[tid] = v;
        __syncthreads();
        #pragma unroll
        for (int off = 1; off < 1024; off <<= 1) {
            int t = (tid >= off) ? buf[tid - off] : 0;
            __syncthreads();
            buf[tid] += t;
            __syncthreads();
        }
        int incl = buf[tid];
        int excl = incl - v;
        if (i < N) row_ptr[i] = carry + excl;
        __syncthreads();
        if (tid == 1023) carry += incl;
        __syncthreads();
    }
    if (tid == 0) row_ptr[N] = carry;
}

__global__ void k_scatter(const int* __restrict__ src, const int* __restrict__ dst,
                          const float* __restrict__ dis, const int* __restrict__ row_ptr,
                          int* __restrict__ fill, int* __restrict__ col,
                          float* __restrict__ val, int E) {
    int e = blockIdx.x * blockDim.x + threadIdx.x;
    if (e >= E) return;
    int s = src[e], d = dst[e];
    if (s == d) return;
    float nv = dis[s] * dis[d];
    int p = atomicAdd(&fill[d], 1);
    int idx = row_ptr[d] + p;
    col[idx] = s;
    val[idx] = nv;
}

// ---------------- Laplacian (pull, CSR by dst) ----------------
// out[n][c] = alpha * ( -sum_j val[j] * xin[col[j]][c] ) + beta * xprev[n][c]
template <int C>
__global__ void __launch_bounds__(256) k_lap(float* __restrict__ out,
                                             const float* __restrict__ xin,
                                             const float* __restrict__ xprev,
                                             float alpha, float beta,
                                             const int* __restrict__ row_ptr,
                                             const int* __restrict__ col,
                                             const float* __restrict__ val, int N) {
    constexpr int NPB = 256 / C;
    int node = blockIdx.x * NPB + threadIdx.x / C;
    int c = threadIdx.x % C;
    if (node >= N) return;
    int beg = row_ptr[node], end = row_ptr[node + 1];
    float acc = 0.f;
    for (int j = beg; j < end; ++j) {
        int s = col[j];
        float nv = val[j];
        acc -= nv * xin[(size_t)s * C + c];
    }
    float r = alpha * acc;
    if (beta != 0.f) r += beta * xprev[(size_t)node * C + c];
    out[(size_t)node * C + c] = r;
}

// ---------------- gate GEMM accumulate ----------------
// G[n][o] += sum_c T[n][c] * Wsrc[g][k][c][h]   (o = g*32+h, 4 gates, K=5)
template <int C>
__global__ void __launch_bounds__(256) k_gemm_acc(float* __restrict__ G,
                                                  const float* __restrict__ T,
                                                  const float* __restrict__ Wsrc,
                                                  int k, int N) {
    __shared__ float Ws[C * 128];
    __shared__ float Ts[16][C];
    int tid = threadIdx.x;
    for (int i = tid; i < C * 128; i += 256) {
        int c = i >> 7, o = i & 127;
        int g = o >> 5, h = o & 31;
        Ws[i] = Wsrc[(((g * KCH + k) * C + c) * 32) + h];
    }
    int base = blockIdx.x * 16;
    for (int i = tid; i < 16 * C; i += 256) {
        int nn = base + i / C;
        Ts[i / C][i % C] = (nn < N) ? T[(size_t)nn * C + (i % C)] : 0.f;
    }
    __syncthreads();
    int o = tid & 127;
    int nl0 = tid >> 7;
    for (int nl = nl0; nl < 16; nl += 2) {
        int node = base + nl;
        if (node < N) {
            float acc = 0.f;
            #pragma unroll
            for (int c = 0; c < C; ++c) acc += Ts[nl][c] * Ws[c * 128 + o];
            G[(size_t)node * 128 + o] += acc;
        }
    }
}

// G[n][o] = b_gates[o]  (b_gates flat [4][32] matches o = g*32+h)
__global__ void k_bias(float* __restrict__ G, const float* __restrict__ bg, int N) {
    int idx = blockIdx.x * blockDim.x + threadIdx.x;
    if (idx >= N * 128) return;
    G[idx] = bg[idx & 127];
}

// ---------------- pointwise LSTM gates ----------------
__global__ void k_gates(const float* __restrict__ G, const float* __restrict__ w_c,
                        float* __restrict__ Cst, float* __restrict__ H, int N) {
    int idx = blockIdx.x * blockDim.x + threadIdx.x;
    if (idx >= N * HID) return;
    int n = idx / HID, h = idx % HID;
    const float* g = G + (size_t)n * 128;
    float Cold = Cst[idx];
    float I = sigmoidf_(g[h]       + w_c[h]        * Cold);
    float F = sigmoidf_(g[32 + h]  + w_c[32 + h]   * Cold);
    float Tg = tanhf(g[64 + h]);
    float Cn = F * Cold + I * Tg;
    float O = sigmoidf_(g[96 + h]  + w_c[64 + h]   * Cn);
    Cst[idx] = Cn;
    H[idx] = O * tanhf(Cn);
}

// out[n][p] = sum_h relu(H[n][h]) * W_lin[p][h] + b_lin[p]
__global__ void k_out(const float* __restrict__ H, const float* __restrict__ W_lin,
                      const float* __restrict__ b_lin, float* __restrict__ out, int N) {
    int idx = blockIdx.x * blockDim.x + threadIdx.x;
    if (idx >= N * PERIODS) return;
    int n = idx / PERIODS, p = idx % PERIODS;
    float acc = b_lin[p];
    #pragma unroll
    for (int h = 0; h < HID; ++h)
        acc += fmaxf(H[(size_t)n * HID + h], 0.f) * W_lin[p * HID + h];
    out[idx] = acc;
}

// ---------------- launch ----------------

extern "C" void kernel_launch(void* const* d_in, const int* in_sizes, int n_in,
                              void* d_out, int out_size, void* d_ws, size_t ws_size,
                              hipStream_t stream) {
    const float* xall  = (const float*)d_in[0];  // [T][N][F_IN]
    const int*   ei    = (const int*)d_in[1];    // [2][E]
    const float* Wx    = (const float*)d_in[2];  // [4][K][F_IN][HID]
    const float* Wh    = (const float*)d_in[3];  // [4][K][HID][HID]
    const float* w_c   = (const float*)d_in[4];  // [3][HID]
    const float* bg    = (const float*)d_in[5];  // [4][HID]
    const float* W_lin = (const float*)d_in[6];  // [P][HID]
    const float* b_lin = (const float*)d_in[7];  // [P]
    float* out = (float*)d_out;

    const int E = in_sizes[1] / 2;
    const int N = in_sizes[0] / (T_STEPS * F_IN);
    const int* src = ei;
    const int* dst = ei + E;

    // workspace carve (256B aligned). Zeroed block first: deg, cnt, fill, H, Cst.
    char* p = (char*)d_ws;
    auto carve = [&](size_t bytes) -> void* {
        void* r = (void*)p;
        p += (bytes + 255) & ~(size_t)255;
        return r;
    };
    char* zero_begin = p;
    float* deg  = (float*)carve((size_t)N * 4);
    int*   cnt  = (int*)  carve((size_t)N * 4);
    int*   fill = (int*)  carve((size_t)N * 4);
    float* H    = (float*)carve((size_t)N * HID * 4);
    float* Cst  = (float*)carve((size_t)N * HID * 4);
    size_t zero_bytes = (size_t)(p - zero_begin);
    float* dis    = (float*)carve((size_t)N * 4);
    int*   rowptr = (int*)  carve((size_t)(N + 1) * 4);
    int*   col    = (int*)  carve((size_t)E * 4);
    float* val    = (float*)carve((size_t)E * 4);
    float* Ta     = (float*)carve((size_t)N * HID * 4);
    float* Tb     = (float*)carve((size_t)N * HID * 4);
    float* Tc     = (float*)carve((size_t)N * HID * 4);
    float* G      = (float*)carve((size_t)N * 128 * 4);

    hipMemsetAsync(zero_begin, 0, zero_bytes, stream);

    const int TB = 256;
    // graph setup
    k_count<<<(E + TB - 1) / TB, TB, 0, stream>>>(src, dst, deg, cnt, E);
    k_dis<<<(N + TB - 1) / TB, TB, 0, stream>>>(deg, dis, N);
    k_scan<<<1, 1024, 0, stream>>>(cnt, rowptr, N);
    k_scatter<<<(E + TB - 1) / TB, TB, 0, stream>>>(src, dst, dis, rowptr, fill, col, val, E);

    const int gemm_grid = (N + 15) / 16;
    const int lap_grid_x = (N + (256 / F_IN) - 1) / (256 / F_IN);
    const int lap_grid_h = (N + (256 / HID) - 1) / (256 / HID);

    for (int t = 0; t < T_STEPS; ++t) {
        const float* xt = xall + (size_t)t * N * F_IN;
        k_bias<<<(N * 128 + TB - 1) / TB, TB, 0, stream>>>(G, bg, N);

        // ---- x phase (C = F_IN = 8), Chebyshev k = 0..4 ----
        k_gemm_acc<F_IN><<<gemm_grid, TB, 0, stream>>>(G, xt, Wx, 0, N);
        k_lap<F_IN><<<lap_grid_x, TB, 0, stream>>>(Ta, xt, nullptr, 1.f, 0.f, rowptr, col, val, N);
        k_gemm_acc<F_IN><<<gemm_grid, TB, 0, stream>>>(G, Ta, Wx, 1, N);
        k_lap<F_IN><<<lap_grid_x, TB, 0, stream>>>(Tb, Ta, xt, 2.f, -1.f, rowptr, col, val, N);
        k_gemm_acc<F_IN><<<gemm_grid, TB, 0, stream>>>(G, Tb, Wx, 2, N);
        k_lap<F_IN><<<lap_grid_x, TB, 0, stream>>>(Tc, Tb, Ta, 2.f, -1.f, rowptr, col, val, N);
        k_gemm_acc<F_IN><<<gemm_grid, TB, 0, stream>>>(G, Tc, Wx, 3, N);
        k_lap<F_IN><<<lap_grid_x, TB, 0, stream>>>(Ta, Tc, Tb, 2.f, -1.f, rowptr, col, val, N);
        k_gemm_acc<F_IN><<<gemm_grid, TB, 0, stream>>>(G, Ta, Wx, 4, N);

        // ---- H phase (C = HID = 32), Chebyshev k = 0..4 ----
        k_gemm_acc<HID><<<gemm_grid, TB, 0, stream>>>(G, H, Wh, 0, N);
        k_lap<HID><<<lap_grid_h, TB, 0, stream>>>(Ta, H, nullptr, 1.f, 0.f, rowptr, col, val, N);
        k_gemm_acc<HID><<<gemm_grid, TB, 0, stream>>>(G, Ta, Wh, 1, N);
        k_lap<HID><<<lap_grid_h, TB, 0, stream>>>(Tb, Ta, H, 2.f, -1.f, rowptr, col, val, N);
        k_gemm_acc<HID><<<gemm_grid, TB, 0, stream>>>(G, Tb, Wh, 2, N);
        k_lap<HID><<<lap_grid_h, TB, 0, stream>>>(Tc, Tb, Ta, 2.f, -1.f, rowptr, col, val, N);
        k_gemm_acc<HID><<<gemm_grid, TB, 0, stream>>>(G, Tc, Wh, 3, N);
        k_lap<HID><<<lap_grid_h, TB, 0, stream>>>(Ta, Tc, Tb, 2.f, -1.f, rowptr, col, val, N);
        k_gemm_acc<HID><<<gemm_grid, TB, 0, stream>>>(G, Ta, Wh, 4, N);

        // ---- pointwise LSTM ----
        k_gates<<<(N * HID + TB - 1) / TB, TB, 0, stream>>>(G, w_c, Cst, H, N);
    }

    k_out<<<(N * PERIODS + TB - 1) / TB, TB, 0, stream>>>(H, W_lin, b_lin, out, N);
}

// Round 2
// 1678.418 us; speedup vs baseline: 1.6606x; 1.6606x over previous
//
#include <hip/hip_runtime.h>
#include <math.h>

#define T_STEPS 8
#define F_IN    8
#define HID     32
#define KCH     5
#define PERIODS 8

__device__ __forceinline__ float sigmoidf_(float x) { return 1.f / (1.f + __expf(-x)); }

// ---------------- graph setup ----------------

__global__ void k_count(const int* __restrict__ src, const int* __restrict__ dst,
                        float* __restrict__ deg, int* __restrict__ cnt, int E) {
    int e = blockIdx.x * blockDim.x + threadIdx.x;
    if (e >= E) return;
    int s = src[e], d = dst[e];
    if (s != d) {
        atomicAdd(&deg[s], 1.f);
        atomicAdd(&cnt[d], 1);
    }
}

__global__ void k_dis(const float* __restrict__ deg, float* __restrict__ dis, int N) {
    int n = blockIdx.x * blockDim.x + threadIdx.x;
    if (n >= N) return;
    float d = deg[n];
    dis[n] = (d > 0.f) ? rsqrtf(d) : 0.f;
}

// exclusive scan of cnt[0..N) -> row_ptr[0..N]. Single block, 1024 threads,
// 32 contiguous elements per thread, 2 barriers total (vs ~600 in round 1).
// Valid for N <= 32768.
__global__ void __launch_bounds__(1024) k_scan(const int* __restrict__ cnt,
                                               int* __restrict__ row_ptr, int N) {
    __shared__ int wsum[16];
    int tid = threadIdx.x;
    int base = tid * 32;
    int v[32];
    int s = 0;
    #pragma unroll
    for (int i = 0; i < 32; ++i) {
        int idx = base + i;
        int t = (idx < N) ? cnt[idx] : 0;
        v[i] = t; s += t;
    }
    int lane = tid & 63, wave = tid >> 6;
    int incl = s;
    #pragma unroll
    for (int off = 1; off < 64; off <<= 1) {
        int t = __shfl_up(incl, off, 64);
        if (lane >= off) incl += t;
    }
    if (lane == 63) wsum[wave] = incl;
    __syncthreads();
    if (tid < 64) {
        int w = (tid < 16) ? wsum[tid] : 0;
        int iw = w;
        #pragma unroll
        for (int off = 1; off < 16; off <<= 1) {
            int t = __shfl_up(iw, off, 64);
            if (tid >= off) iw += t;
        }
        if (tid < 16) wsum[tid] = iw - w;  // exclusive wave prefix
    }
    __syncthreads();
    int excl = wsum[wave] + (incl - s);
    #pragma unroll
    for (int i = 0; i < 32; ++i) {
        int idx = base + i;
        if (idx < N) row_ptr[idx] = excl;
        excl += v[i];
    }
    if (tid == 1023) row_ptr[N] = wsum[15] + incl;  // grand total
}

__global__ void k_scatter(const int* __restrict__ src, const int* __restrict__ dst,
                          const float* __restrict__ dis, const int* __restrict__ row_ptr,
                          int* __restrict__ fill, int* __restrict__ col,
                          float* __restrict__ val, int E) {
    int e = blockIdx.x * blockDim.x + threadIdx.x;
    if (e >= E) return;
    int s = src[e], d = dst[e];
    if (s == d) return;
    float nv = dis[s] * dis[d];
    int p = atomicAdd(&fill[d], 1);
    int idx = row_ptr[d] + p;
    col[idx] = s;
    val[idx] = nv;
}

// ---------------- Laplacian (pull, CSR by dst, float4 gather) ----------------
// out[n][c] = alpha * ( -sum_j val[j] * xin[col[j]][c] ) + beta * xprev[n][c]
template <int C>
__global__ void __launch_bounds__(256) k_lap4(float* __restrict__ outp,
                                              const float* __restrict__ xin,
                                              const float* __restrict__ xprev,
                                              float alpha, float beta,
                                              const int* __restrict__ rowptr,
                                              const int* __restrict__ col,
                                              const float* __restrict__ val, int N) {
    constexpr int Q = C / 4;                 // lanes per node
    int idx = blockIdx.x * 256 + threadIdx.x;
    int node = idx / Q, q = idx % Q;
    if (node >= N) return;
    int beg = rowptr[node], end = rowptr[node + 1];
    float ax = 0.f, ay = 0.f, az = 0.f, aw = 0.f;
    for (int j = beg; j < end; ++j) {
        int s = col[j];
        float nv = val[j];
        float4 xv = *(const float4*)(xin + (size_t)s * C + q * 4);
        ax -= nv * xv.x; ay -= nv * xv.y; az -= nv * xv.z; aw -= nv * xv.w;
    }
    size_t off = (size_t)node * C + q * 4;
    float4 r;
    if (beta != 0.f) {
        float4 pv = *(const float4*)(xprev + off);
        r.x = alpha * ax + beta * pv.x;
        r.y = alpha * ay + beta * pv.y;
        r.z = alpha * az + beta * pv.z;
        r.w = alpha * aw + beta * pv.w;
    } else {
        r.x = alpha * ax; r.y = alpha * ay; r.z = alpha * az; r.w = alpha * aw;
    }
    *(float4*)(outp + off) = r;
}

// ---------------- fused gate GEMM + LSTM pointwise ----------------
// Per block: 16 nodes. Gate pre-acts = bias + [x-terms 40] @ Wx + [H-terms 160] @ Wh,
// all in registers; LSTM nonlinearities applied via an 8KB LDS stage. Writes H
// (into THall slice 0) and Cst only — no G buffer in global memory.
__global__ void __launch_bounds__(256) k_step(
    const float* __restrict__ xt,    // [N][8]  (timestep slice)
    const float* __restrict__ TX,    // [4][N][8]   Chebyshev terms k=1..4 of x
    float* __restrict__ THall,       // [5][N][32]  slice 0 = H (in/out), 1..4 = terms
    float* __restrict__ Cst,         // [N][32]
    const float* __restrict__ Wx,    // [4][5][8][32]
    const float* __restrict__ Wh,    // [4][5][32][32]
    const float* __restrict__ w_c,   // [3][32]
    const float* __restrict__ bg,    // [4][32]
    int N) {
    __shared__ float smem[40 * 128];     // W chunk buffer; reused as gate stage
    __shared__ float Tbuf[16][200];      // per-node inputs: [0..39]=x-terms, [40..199]=H-terms
    int tid = threadIdx.x;
    int o = tid & 127, nl0 = tid >> 7;
    int base = blockIdx.x * 16;

    // stage T: x part (k-major, 40 floats/node as 10 float4s)
    for (int i = tid; i < 160; i += 256) {
        int nl = i / 10, w = i % 10;
        int node = base + nl; if (node >= N) node = N - 1;
        int k = w >> 1, c0 = (w & 1) * 4;
        const float* src = (k == 0) ? (xt + (size_t)node * 8 + c0)
                                    : (TX + (((size_t)(k - 1) * N + node) * 8 + c0));
        float4 v = *(const float4*)src;
        Tbuf[nl][w * 4 + 0] = v.x; Tbuf[nl][w * 4 + 1] = v.y;
        Tbuf[nl][w * 4 + 2] = v.z; Tbuf[nl][w * 4 + 3] = v.w;
    }
    // stage T: H part (k-major, 160 floats/node as 40 float4s)
    for (int i = tid; i < 640; i += 256) {
        int nl = i / 40, w = i % 40;
        int node = base + nl; if (node >= N) node = N - 1;
        int k = w >> 3, c0 = (w & 7) * 4;
        float4 v = *(const float4*)(THall + ((size_t)k * N + node) * 32 + c0);
        Tbuf[nl][40 + w * 4 + 0] = v.x; Tbuf[nl][40 + w * 4 + 1] = v.y;
        Tbuf[nl][40 + w * 4 + 2] = v.z; Tbuf[nl][40 + w * 4 + 3] = v.w;
    }

    float acc[8];
    float b = bg[o];
    #pragma unroll
    for (int j = 0; j < 8; ++j) acc[j] = b;

    // chunk 0: x-terms (40 inputs). W layout Wx[g][k][c][h], o = g*32+h.
    for (int i = tid; i < 40 * 128; i += 256) {
        int ci = i >> 7, oo = i & 127;
        int g = oo >> 5, h = oo & 31, k = ci >> 3, c = ci & 7;
        smem[i] = Wx[(((g * KCH + k) * 8) + c) * 32 + h];
    }
    __syncthreads();
    #pragma unroll 4
    for (int c = 0; c < 40; ++c) {
        float w = smem[c * 128 + o];
        #pragma unroll
        for (int j = 0; j < 8; ++j) acc[j] += Tbuf[nl0 + 2 * j][c] * w;
    }
    // chunks 1..5: H-terms, k = 0..4 (32 inputs each)
    for (int k = 0; k < KCH; ++k) {
        __syncthreads();
        for (int i = tid; i < 32 * 128; i += 256) {
            int ci = i >> 7, oo = i & 127;
            int g = oo >> 5, h = oo & 31;
            smem[i] = Wh[(((g * KCH + k) * 32) + ci) * 32 + h];
        }
        __syncthreads();
        int cb = 40 + k * 32;
        #pragma unroll 4
        for (int c = 0; c < 32; ++c) {
            float w = smem[c * 128 + o];
            #pragma unroll
            for (int j = 0; j < 8; ++j) acc[j] += Tbuf[nl0 + 2 * j][cb + c] * w;
        }
    }
    __syncthreads();
    // gate stage into smem (aliases dead W buffer)
    #pragma unroll
    for (int j = 0; j < 8; ++j) smem[(nl0 + 2 * j) * 128 + o] = acc[j];
    __syncthreads();
    // LSTM pointwise: 512 (node,h) pairs
    for (int p = tid; p < 512; p += 256) {
        int nl = p >> 5, h = p & 31;
        int node = base + nl;
        if (node < N) {
            const float* g = smem + nl * 128;
            size_t idx = (size_t)node * 32 + h;
            float Cold = Cst[idx];
            float I  = sigmoidf_(g[h]      + w_c[h]      * Cold);
            float F  = sigmoidf_(g[32 + h] + w_c[32 + h] * Cold);
            float Tg = tanhf(g[64 + h]);
            float Cn = F * Cold + I * Tg;
            float O  = sigmoidf_(g[96 + h] + w_c[64 + h] * Cn);
            Cst[idx] = Cn;
            THall[idx] = O * tanhf(Cn);   // slice 0 = new H
        }
    }
}

// out[n][p] = sum_h relu(H[n][h]) * W_lin[p][h] + b_lin[p]
__global__ void k_out(const float* __restrict__ H, const float* __restrict__ W_lin,
                      const float* __restrict__ b_lin, float* __restrict__ out, int N) {
    int idx = blockIdx.x * blockDim.x + threadIdx.x;
    if (idx >= N * PERIODS) return;
    int n = idx / PERIODS, p = idx % PERIODS;
    float acc = b_lin[p];
    #pragma unroll
    for (int h = 0; h < HID; ++h)
        acc += fmaxf(H[(size_t)n * HID + h], 0.f) * W_lin[p * HID + h];
    out[idx] = acc;
}

// ---------------- launch ----------------

extern "C" void kernel_launch(void* const* d_in, const int* in_sizes, int n_in,
                              void* d_out, int out_size, void* d_ws, size_t ws_size,
                              hipStream_t stream) {
    const float* xall  = (const float*)d_in[0];  // [T][N][F_IN]
    const int*   ei    = (const int*)d_in[1];    // [2][E]
    const float* Wx    = (const float*)d_in[2];  // [4][K][F_IN][HID]
    const float* Wh    = (const float*)d_in[3];  // [4][K][HID][HID]
    const float* w_c   = (const float*)d_in[4];  // [3][HID]
    const float* bg    = (const float*)d_in[5];  // [4][HID]
    const float* W_lin = (const float*)d_in[6];  // [P][HID]
    const float* b_lin = (const float*)d_in[7];  // [P]
    float* out = (float*)d_out;

    const int E = in_sizes[1] / 2;
    const int N = in_sizes[0] / (T_STEPS * F_IN);
    const int* src = ei;
    const int* dst = ei + E;

    char* p = (char*)d_ws;
    auto carve = [&](size_t bytes) -> void* {
        void* r = (void*)p;
        p += (bytes + 255) & ~(size_t)255;
        return r;
    };
    // zero block: deg, cnt, fill, Cst, THall slice 0 (= H0)
    char* zero_begin = p;
    float* deg  = (float*)carve((size_t)N * 4);
    int*   cnt  = (int*)  carve((size_t)N * 4);
    int*   fill = (int*)  carve((size_t)N * 4);
    float* Cst  = (float*)carve((size_t)N * HID * 4);
    float* THall = (float*)carve((size_t)KCH * N * HID * 4);  // slice 0 first
    size_t zero_bytes = (size_t)((char*)THall - zero_begin) + (size_t)N * HID * 4;
    float* dis    = (float*)carve((size_t)N * 4);
    int*   rowptr = (int*)  carve((size_t)(N + 1) * 4);
    int*   col    = (int*)  carve((size_t)E * 4);
    float* val    = (float*)carve((size_t)E * 4);
    float* TX     = (float*)carve((size_t)4 * N * F_IN * 4);  // x Cheb terms k=1..4

    hipMemsetAsync(zero_begin, 0, zero_bytes, stream);

    const int TB = 256;
    k_count<<<(E + TB - 1) / TB, TB, 0, stream>>>(src, dst, deg, cnt, E);
    k_dis<<<(N + TB - 1) / TB, TB, 0, stream>>>(deg, dis, N);
    k_scan<<<1, 1024, 0, stream>>>(cnt, rowptr, N);
    k_scatter<<<(E + TB - 1) / TB, TB, 0, stream>>>(src, dst, dis, rowptr, fill, col, val, E);

    const int lapx_grid = (N * (F_IN / 4) + TB - 1) / TB;   // Q=2
    const int laph_grid = (N * (HID / 4) + TB - 1) / TB;    // Q=8
    const int step_grid = (N + 15) / 16;

    float* TX1 = TX;
    float* TX2 = TX + (size_t)N * F_IN;
    float* TX3 = TX + (size_t)2 * N * F_IN;
    float* TX4 = TX + (size_t)3 * N * F_IN;
    float* TH0 = THall;                           // = H
    float* TH1 = THall + (size_t)N * HID;
    float* TH2 = THall + (size_t)2 * N * HID;
    float* TH3 = THall + (size_t)3 * N * HID;
    float* TH4 = THall + (size_t)4 * N * HID;

    for (int t = 0; t < T_STEPS; ++t) {
        const float* xt = xall + (size_t)t * N * F_IN;

        // x-phase Chebyshev terms (C=8)
        k_lap4<F_IN><<<lapx_grid, TB, 0, stream>>>(TX1, xt,  nullptr, 1.f,  0.f, rowptr, col, val, N);
        k_lap4<F_IN><<<lapx_grid, TB, 0, stream>>>(TX2, TX1, xt,      2.f, -1.f, rowptr, col, val, N);
        k_lap4<F_IN><<<lapx_grid, TB, 0, stream>>>(TX3, TX2, TX1,     2.f, -1.f, rowptr, col, val, N);
        k_lap4<F_IN><<<lapx_grid, TB, 0, stream>>>(TX4, TX3, TX2,     2.f, -1.f, rowptr, col, val, N);

        // H-phase Chebyshev terms (C=32); TH0 holds current H
        k_lap4<HID><<<laph_grid, TB, 0, stream>>>(TH1, TH0, nullptr, 1.f,  0.f, rowptr, col, val, N);
        k_lap4<HID><<<laph_grid, TB, 0, stream>>>(TH2, TH1, TH0,     2.f, -1.f, rowptr, col, val, N);
        k_lap4<HID><<<laph_grid, TB, 0, stream>>>(TH3, TH2, TH1,     2.f, -1.f, rowptr, col, val, N);
        k_lap4<HID><<<laph_grid, TB, 0, stream>>>(TH4, TH3, TH2,     2.f, -1.f, rowptr, col, val, N);

        // fused gate GEMM + LSTM pointwise (writes TH0 = new H, Cst)
        k_step<<<step_grid, TB, 0, stream>>>(xt, TX, THall, Cst, Wx, Wh, w_c, bg, N);
    }

    k_out<<<(N * PERIODS + TB - 1) / TB, TB, 0, stream>>>(TH0, W_lin, b_lin, out, N);
}

// Round 3
// 1371.413 us; speedup vs baseline: 2.0323x; 1.2239x over previous
//
#include <hip/hip_runtime.h>
#include <math.h>

#define T_STEPS 8
#define F_IN    8
#define HID     32
#define KCH     5
#define PERIODS 8

__device__ __forceinline__ float sigmoidf_(float x) { return 1.f / (1.f + __expf(-x)); }

// ---------------- graph setup ----------------

__global__ void k_count(const int* __restrict__ src, const int* __restrict__ dst,
                        int* __restrict__ degi, int* __restrict__ cnt, int E) {
    int e = blockIdx.x * blockDim.x + threadIdx.x;
    if (e >= E) return;
    int s = src[e], d = dst[e];
    if (s != d) {
        atomicAdd(&degi[s], 1);
        atomicAdd(&cnt[d], 1);
    }
}

__global__ void k_dis(const int* __restrict__ degi, float* __restrict__ dis, int N) {
    int n = blockIdx.x * blockDim.x + threadIdx.x;
    if (n >= N) return;
    int d = degi[n];
    dis[n] = (d > 0) ? rsqrtf((float)d) : 0.f;
}

// exclusive scan of cnt[0..N) -> row_ptr[0..N]. Single block, 1024 threads,
// 32 elems/thread, 2 barriers. Valid for N <= 32768.
__global__ void __launch_bounds__(1024) k_scan(const int* __restrict__ cnt,
                                               int* __restrict__ row_ptr, int N) {
    __shared__ int wsum[16];
    int tid = threadIdx.x;
    int base = tid * 32;
    int v[32];
    int s = 0;
    #pragma unroll
    for (int i = 0; i < 32; ++i) {
        int idx = base + i;
        int t = (idx < N) ? cnt[idx] : 0;
        v[i] = t; s += t;
    }
    int lane = tid & 63, wave = tid >> 6;
    int incl = s;
    #pragma unroll
    for (int off = 1; off < 64; off <<= 1) {
        int t = __shfl_up(incl, off, 64);
        if (lane >= off) incl += t;
    }
    if (lane == 63) wsum[wave] = incl;
    __syncthreads();
    if (tid < 64) {
        int w = (tid < 16) ? wsum[tid] : 0;
        int iw = w;
        #pragma unroll
        for (int off = 1; off < 16; off <<= 1) {
            int t = __shfl_up(iw, off, 64);
            if (tid >= off) iw += t;
        }
        if (tid < 16) wsum[tid] = iw - w;  // exclusive wave prefix
    }
    __syncthreads();
    int excl = wsum[wave] + (incl - s);
    #pragma unroll
    for (int i = 0; i < 32; ++i) {
        int idx = base + i;
        if (idx < N) row_ptr[idx] = excl;
        excl += v[i];
    }
    if (tid == 1023) row_ptr[N] = wsum[15] + incl;
}

__global__ void k_scatter(const int* __restrict__ src, const int* __restrict__ dst,
                          const float* __restrict__ dis, const int* __restrict__ row_ptr,
                          int* __restrict__ fill, int* __restrict__ col,
                          float* __restrict__ val, int E) {
    int e = blockIdx.x * blockDim.x + threadIdx.x;
    if (e >= E) return;
    int s = src[e], d = dst[e];
    if (s == d) return;
    float nv = dis[s] * dis[d];
    int p = atomicAdd(&fill[d], 1);
    int idx = row_ptr[d] + p;
    col[idx] = s;
    val[idx] = nv;
}

// transpose x: [T][N][8] -> xb [N][64]  (node-major, t*8+c inner)
__global__ void k_xt(const float* __restrict__ xall, float* __restrict__ xb, int N) {
    int i = blockIdx.x * blockDim.x + threadIdx.x;
    if (i >= N * T_STEPS) return;
    int n = i >> 3, t = i & 7;
    float4 a = *(const float4*)(xall + ((size_t)t * N + n) * 8);
    float4 b = *(const float4*)(xall + ((size_t)t * N + n) * 8 + 4);
    *(float4*)(xb + (size_t)n * 64 + t * 8) = a;
    *(float4*)(xb + (size_t)n * 64 + t * 8 + 4) = b;
}

// ---------------- Laplacian (pull, CSR by dst, float4 gather) ----------------
// out[n][c] = alpha * ( -sum_j val[j] * xin[col[j]][c] ) + beta * xprev[n][c]
template <int C>
__global__ void __launch_bounds__(256) k_lap4(float* __restrict__ outp,
                                              const float* __restrict__ xin,
                                              const float* __restrict__ xprev,
                                              float alpha, float beta,
                                              const int* __restrict__ rowptr,
                                              const int* __restrict__ col,
                                              const float* __restrict__ val, int N) {
    constexpr int Q = C / 4;
    int idx = blockIdx.x * 256 + threadIdx.x;
    int node = idx / Q, q = idx % Q;
    if (node >= N) return;
    int beg = rowptr[node], end = rowptr[node + 1];
    float ax = 0.f, ay = 0.f, az = 0.f, aw = 0.f;
    for (int j = beg; j < end; ++j) {
        int s = col[j];
        float nv = val[j];
        float4 xv = *(const float4*)(xin + (size_t)s * C + q * 4);
        ax -= nv * xv.x; ay -= nv * xv.y; az -= nv * xv.z; aw -= nv * xv.w;
    }
    size_t off = (size_t)node * C + q * 4;
    float4 r;
    if (beta != 0.f) {
        float4 pv = *(const float4*)(xprev + off);
        r.x = alpha * ax + beta * pv.x;
        r.y = alpha * ay + beta * pv.y;
        r.z = alpha * az + beta * pv.z;
        r.w = alpha * aw + beta * pv.w;
    } else {
        r.x = alpha * ax; r.y = alpha * ay; r.z = alpha * az; r.w = alpha * aw;
    }
    *(float4*)(outp + off) = r;
}

// ---------------- fused gate GEMM + LSTM pointwise (register-blocked) --------
// 128 nodes/block, 256 threads. Thread tile: 8 nodes x 8 outputs in registers.
// GEMM runs in 6 LDS chunks (40 x-term inputs, then 5x32 H-term inputs).
// Inner iter: 4 ds_read_b128 + 64 v_fma. Gate nonlinearities via 64KB LDS stage.
#define NB 128
#define TSLD 132   // Ts row stride (pad 128->132, float4-aligned, debanked)

__global__ void __launch_bounds__(256, 1) k_step(
    const float* __restrict__ xb,    // [N][64]
    const float* __restrict__ TXB,   // [4][N][64]  x Cheb terms k=1..4
    float* __restrict__ THall,       // [5][N][32]  slice 0 = H (in/out), 1..4 terms
    float* __restrict__ Cst,         // [N][32]
    const float* __restrict__ Wx,    // [4][5][8][32]
    const float* __restrict__ Wh,    // [4][5][32][32]
    const float* __restrict__ w_c,   // [3][32]
    const float* __restrict__ bg,    // [4][32]
    int t, int N) {
    __shared__ float smem[16384];            // 64 KB: Ws[0..5120) + Ts[5120..10400); later Gbuf[128][128]
    float* Ws = smem;
    float* Ts = smem + 5120;
    int tid = threadIdx.x;
    int base = blockIdx.x * NB;
    int o0 = (tid & 15) * 8;                 // output tile start
    int n0 = (tid >> 4) * 8;                 // node tile start (local)

    float acc[8][8];
    {
        float4 bA = *(const float4*)(bg + o0);
        float4 bB = *(const float4*)(bg + o0 + 4);
        #pragma unroll
        for (int nj = 0; nj < 8; ++nj) {
            acc[nj][0] = bA.x; acc[nj][1] = bA.y; acc[nj][2] = bA.z; acc[nj][3] = bA.w;
            acc[nj][4] = bB.x; acc[nj][5] = bB.y; acc[nj][6] = bB.z; acc[nj][7] = bB.w;
        }
    }

    // ---- chunk 0: x-terms (40 c = 5 k-terms x 8 channels) ----
    for (int i = tid; i < 5 * 8 * 128; i += 256) {       // Ws: 40x128
        int ci = i >> 7, o = i & 127;
        int k = ci >> 3, c = ci & 7, g = o >> 5, h = o & 31;
        Ws[i] = Wx[(((g * KCH + k) * 8) + c) * 32 + h];
    }
    for (int i = tid; i < NB * 10; i += 256) {           // Ts: 40x128 (transposed stage)
        int nl = i / 10, w = i % 10;
        int node = base + nl; if (node >= N) node = N - 1;
        int k = w >> 1, cc0 = (w & 1) * 4;
        const float* sp = (k == 0) ? (xb + (size_t)node * 64 + t * 8 + cc0)
                                   : (TXB + (((size_t)(k - 1) * N + node) * 64) + t * 8 + cc0);
        float4 v = *(const float4*)sp;
        int row = k * 8 + cc0;
        Ts[(row + 0) * TSLD + nl] = v.x;
        Ts[(row + 1) * TSLD + nl] = v.y;
        Ts[(row + 2) * TSLD + nl] = v.z;
        Ts[(row + 3) * TSLD + nl] = v.w;
    }
    __syncthreads();
    #pragma unroll 2
    for (int c = 0; c < 40; ++c) {
        float4 wA = *(const float4*)&Ws[c * 128 + o0];
        float4 wB = *(const float4*)&Ws[c * 128 + o0 + 4];
        float4 tA = *(const float4*)&Ts[c * TSLD + n0];
        float4 tB = *(const float4*)&Ts[c * TSLD + n0 + 4];
        float tv[8] = {tA.x, tA.y, tA.z, tA.w, tB.x, tB.y, tB.z, tB.w};
        float wv[8] = {wA.x, wA.y, wA.z, wA.w, wB.x, wB.y, wB.z, wB.w};
        #pragma unroll
        for (int nj = 0; nj < 8; ++nj)
            #pragma unroll
            for (int oj = 0; oj < 8; ++oj)
                acc[nj][oj] += tv[nj] * wv[oj];
    }

    // ---- chunks 1..5: H-terms k=0..4 (32 c each) ----
    for (int k = 0; k < KCH; ++k) {
        __syncthreads();
        for (int i = tid; i < 32 * 128; i += 256) {      // Ws: 32x128
            int ci = i >> 7, o = i & 127;
            int g = o >> 5, h = o & 31;
            Ws[i] = Wh[(((g * KCH + k) * 32) + ci) * 32 + h];
        }
        for (int i = tid; i < NB * 8; i += 256) {        // Ts: 32x128
            int nl = i >> 3, q = i & 7;
            int node = base + nl; if (node >= N) node = N - 1;
            float4 v = *(const float4*)(THall + ((size_t)k * N + node) * 32 + q * 4);
            int row = q * 4;
            Ts[(row + 0) * TSLD + nl] = v.x;
            Ts[(row + 1) * TSLD + nl] = v.y;
            Ts[(row + 2) * TSLD + nl] = v.z;
            Ts[(row + 3) * TSLD + nl] = v.w;
        }
        __syncthreads();
        #pragma unroll 2
        for (int c = 0; c < 32; ++c) {
            float4 wA = *(const float4*)&Ws[c * 128 + o0];
            float4 wB = *(const float4*)&Ws[c * 128 + o0 + 4];
            float4 tA = *(const float4*)&Ts[c * TSLD + n0];
            float4 tB = *(const float4*)&Ts[c * TSLD + n0 + 4];
            float tv[8] = {tA.x, tA.y, tA.z, tA.w, tB.x, tB.y, tB.z, tB.w};
            float wv[8] = {wA.x, wA.y, wA.z, wA.w, wB.x, wB.y, wB.z, wB.w};
            #pragma unroll
            for (int nj = 0; nj < 8; ++nj)
                #pragma unroll
                for (int oj = 0; oj < 8; ++oj)
                    acc[nj][oj] += tv[nj] * wv[oj];
        }
    }

    // ---- stage gate pre-activations into Gbuf = smem[128][128] ----
    __syncthreads();
    #pragma unroll
    for (int nj = 0; nj < 8; ++nj) {
        float4 a = {acc[nj][0], acc[nj][1], acc[nj][2], acc[nj][3]};
        float4 b = {acc[nj][4], acc[nj][5], acc[nj][6], acc[nj][7]};
        *(float4*)&smem[(n0 + nj) * 128 + o0] = a;
        *(float4*)&smem[(n0 + nj) * 128 + o0 + 4] = b;
    }
    __syncthreads();

    // ---- LSTM pointwise ----
    for (int p = tid; p < NB * 32; p += 256) {
        int nl = p >> 5, h = p & 31;
        int node = base + nl;
        if (node < N) {
            const float* g = smem + nl * 128;
            size_t idx = (size_t)node * 32 + h;
            float Cold = Cst[idx];
            float I  = sigmoidf_(g[h]      + w_c[h]      * Cold);
            float F  = sigmoidf_(g[32 + h] + w_c[32 + h] * Cold);
            float Tg = tanhf(g[64 + h]);
            float Cn = F * Cold + I * Tg;
            float O  = sigmoidf_(g[96 + h] + w_c[64 + h] * Cn);
            Cst[idx] = Cn;
            THall[idx] = O * tanhf(Cn);      // slice 0 = new H
        }
    }
}

// out[n][p] = sum_h relu(H[n][h]) * W_lin[p][h] + b_lin[p]
__global__ void k_out(const float* __restrict__ H, const float* __restrict__ W_lin,
                      const float* __restrict__ b_lin, float* __restrict__ out, int N) {
    int idx = blockIdx.x * blockDim.x + threadIdx.x;
    if (idx >= N * PERIODS) return;
    int n = idx / PERIODS, p = idx % PERIODS;
    float acc = b_lin[p];
    #pragma unroll
    for (int h = 0; h < HID; ++h)
        acc += fmaxf(H[(size_t)n * HID + h], 0.f) * W_lin[p * HID + h];
    out[idx] = acc;
}

// ---------------- launch ----------------

extern "C" void kernel_launch(void* const* d_in, const int* in_sizes, int n_in,
                              void* d_out, int out_size, void* d_ws, size_t ws_size,
                              hipStream_t stream) {
    const float* xall  = (const float*)d_in[0];
    const int*   ei    = (const int*)d_in[1];
    const float* Wx    = (const float*)d_in[2];
    const float* Wh    = (const float*)d_in[3];
    const float* w_c   = (const float*)d_in[4];
    const float* bg    = (const float*)d_in[5];
    const float* W_lin = (const float*)d_in[6];
    const float* b_lin = (const float*)d_in[7];
    float* out = (float*)d_out;

    const int E = in_sizes[1] / 2;
    const int N = in_sizes[0] / (T_STEPS * F_IN);
    const int* src = ei;
    const int* dst = ei + E;

    char* p = (char*)d_ws;
    auto carve = [&](size_t bytes) -> void* {
        void* r = (void*)p;
        p += (bytes + 255) & ~(size_t)255;
        return r;
    };
    // zero block: degi, cnt, fill, Cst, THall slice 0 (= H0)
    char* zero_begin = p;
    int*   degi = (int*)  carve((size_t)N * 4);
    int*   cnt  = (int*)  carve((size_t)N * 4);
    int*   fill = (int*)  carve((size_t)N * 4);
    float* Cst  = (float*)carve((size_t)N * HID * 4);
    float* THall = (float*)carve((size_t)KCH * N * HID * 4);
    size_t zero_bytes = (size_t)((char*)THall - zero_begin) + (size_t)N * HID * 4;
    float* dis    = (float*)carve((size_t)N * 4);
    int*   rowptr = (int*)  carve((size_t)(N + 1) * 4);
    int*   col    = (int*)  carve((size_t)E * 4);
    float* val    = (float*)carve((size_t)E * 4);
    float* xb     = (float*)carve((size_t)N * 64 * 4);        // [N][T*8]
    float* TXB    = (float*)carve((size_t)4 * N * 64 * 4);    // x Cheb terms k=1..4

    hipMemsetAsync(zero_begin, 0, zero_bytes, stream);

    const int TB = 256;
    k_count<<<(E + TB - 1) / TB, TB, 0, stream>>>(src, dst, degi, cnt, E);
    k_dis<<<(N + TB - 1) / TB, TB, 0, stream>>>(degi, dis, N);
    k_scan<<<1, 1024, 0, stream>>>(cnt, rowptr, N);
    k_scatter<<<(E + TB - 1) / TB, TB, 0, stream>>>(src, dst, dis, rowptr, fill, col, val, E);
    k_xt<<<(N * T_STEPS + TB - 1) / TB, TB, 0, stream>>>(xall, xb, N);

    // batched x-phase Chebyshev terms over all timesteps (C = 64)
    float* TXB0 = TXB;
    float* TXB1 = TXB + (size_t)N * 64;
    float* TXB2 = TXB + (size_t)2 * N * 64;
    float* TXB3 = TXB + (size_t)3 * N * 64;
    const int lapx_grid = (N * 16 + TB - 1) / TB;
    k_lap4<64><<<lapx_grid, TB, 0, stream>>>(TXB0, xb,   nullptr, 1.f,  0.f, rowptr, col, val, N);
    k_lap4<64><<<lapx_grid, TB, 0, stream>>>(TXB1, TXB0, xb,      2.f, -1.f, rowptr, col, val, N);
    k_lap4<64><<<lapx_grid, TB, 0, stream>>>(TXB2, TXB1, TXB0,    2.f, -1.f, rowptr, col, val, N);
    k_lap4<64><<<lapx_grid, TB, 0, stream>>>(TXB3, TXB2, TXB1,    2.f, -1.f, rowptr, col, val, N);

    const int laph_grid = (N * 8 + TB - 1) / TB;
    const int step_grid = (N + NB - 1) / NB;
    float* TH0 = THall;
    float* TH1 = THall + (size_t)N * HID;
    float* TH2 = THall + (size_t)2 * N * HID;
    float* TH3 = THall + (size_t)3 * N * HID;
    float* TH4 = THall + (size_t)4 * N * HID;

    for (int t = 0; t < T_STEPS; ++t) {
        k_lap4<HID><<<laph_grid, TB, 0, stream>>>(TH1, TH0, nullptr, 1.f,  0.f, rowptr, col, val, N);
        k_lap4<HID><<<laph_grid, TB, 0, stream>>>(TH2, TH1, TH0,     2.f, -1.f, rowptr, col, val, N);
        k_lap4<HID><<<laph_grid, TB, 0, stream>>>(TH3, TH2, TH1,     2.f, -1.f, rowptr, col, val, N);
        k_lap4<HID><<<laph_grid, TB, 0, stream>>>(TH4, TH3, TH2,     2.f, -1.f, rowptr, col, val, N);
        k_step<<<step_grid, TB, 0, stream>>>(xb, TXB, THall, Cst, Wx, Wh, w_c, bg, t, N);
    }

    k_out<<<(N * PERIODS + TB - 1) / TB, TB, 0, stream>>>(TH0, W_lin, b_lin, out, N);
}

// Round 4
// 937.444 us; speedup vs baseline: 2.9732x; 1.4629x over previous
//
#include <hip/hip_runtime.h>
#include <math.h>

#define T_STEPS 8
#define F_IN    8
#define HID     32
#define KCH     5
#define PERIODS 8

__device__ __forceinline__ float sigmoidf_(float x) { return 1.f / (1.f + __expf(-x)); }
__device__ __forceinline__ float tanhf_(float x) {
    float e = __expf(2.f * x);
    return 1.f - 2.f / (e + 1.f);   // safe: x->+inf => 1, x->-inf => -1
}

// ---------------- graph setup ----------------

__global__ void k_count(const int* __restrict__ src, const int* __restrict__ dst,
                        int* __restrict__ degi, int* __restrict__ cnt, int E) {
    int e = blockIdx.x * blockDim.x + threadIdx.x;
    if (e >= E) return;
    int s = src[e], d = dst[e];
    if (s != d) {
        atomicAdd(&degi[s], 1);
        atomicAdd(&cnt[d], 1);
    }
}

__global__ void k_dis(const int* __restrict__ degi, float* __restrict__ dis, int N) {
    int n = blockIdx.x * blockDim.x + threadIdx.x;
    if (n >= N) return;
    int d = degi[n];
    dis[n] = (d > 0) ? rsqrtf((float)d) : 0.f;
}

// exclusive scan of cnt[0..N) -> row_ptr[0..N]. Single block, 1024 threads,
// 32 elems/thread, 2 barriers. Valid for N <= 32768.
__global__ void __launch_bounds__(1024) k_scan(const int* __restrict__ cnt,
                                               int* __restrict__ row_ptr, int N) {
    __shared__ int wsum[16];
    int tid = threadIdx.x;
    int base = tid * 32;
    int v[32];
    int s = 0;
    #pragma unroll
    for (int i = 0; i < 32; ++i) {
        int idx = base + i;
        int t = (idx < N) ? cnt[idx] : 0;
        v[i] = t; s += t;
    }
    int lane = tid & 63, wave = tid >> 6;
    int incl = s;
    #pragma unroll
    for (int off = 1; off < 64; off <<= 1) {
        int t = __shfl_up(incl, off, 64);
        if (lane >= off) incl += t;
    }
    if (lane == 63) wsum[wave] = incl;
    __syncthreads();
    if (tid < 64) {
        int w = (tid < 16) ? wsum[tid] : 0;
        int iw = w;
        #pragma unroll
        for (int off = 1; off < 16; off <<= 1) {
            int t = __shfl_up(iw, off, 64);
            if (tid >= off) iw += t;
        }
        if (tid < 16) wsum[tid] = iw - w;  // exclusive wave prefix
    }
    __syncthreads();
    int excl = wsum[wave] + (incl - s);
    #pragma unroll
    for (int i = 0; i < 32; ++i) {
        int idx = base + i;
        if (idx < N) row_ptr[idx] = excl;
        excl += v[i];
    }
    if (tid == 1023) row_ptr[N] = wsum[15] + incl;
}

// writes packed (col, -norm) per edge slot
__global__ void k_scatter(const int* __restrict__ src, const int* __restrict__ dst,
                          const float* __restrict__ dis, const int* __restrict__ row_ptr,
                          int* __restrict__ fill, int2* __restrict__ cv, int E) {
    int e = blockIdx.x * blockDim.x + threadIdx.x;
    if (e >= E) return;
    int s = src[e], d = dst[e];
    if (s == d) return;
    float nv = -dis[s] * dis[d];     // pre-negated: lap = sum(nv * x)
    int p = atomicAdd(&fill[d], 1);
    cv[row_ptr[d] + p] = make_int2(s, __float_as_int(nv));
}

// transpose x: [T][N][8] -> xb [N][64]  (node-major, t*8+c inner)
__global__ void k_xt(const float* __restrict__ xall, float* __restrict__ xb, int N) {
    int i = blockIdx.x * blockDim.x + threadIdx.x;
    if (i >= N * T_STEPS) return;
    int n = i >> 3, t = i & 7;
    float4 a = *(const float4*)(xall + ((size_t)t * N + n) * 8);
    float4 b = *(const float4*)(xall + ((size_t)t * N + n) * 8 + 4);
    *(float4*)(xb + (size_t)n * 64 + t * 8) = a;
    *(float4*)(xb + (size_t)n * 64 + t * 8 + 4) = b;
}

// ---------------- Laplacian (pull, CSR by dst, packed cv, float4 gather) ----
// out[n][c] = alpha * sum_j val[j]*xin[col[j]][c] + beta * xprev[n][c]
// (val already negated at scatter)
template <int C>
__global__ void __launch_bounds__(256) k_lap4(float* __restrict__ outp,
                                              const float* __restrict__ xin,
                                              const float* __restrict__ xprev,
                                              float alpha, float beta,
                                              const int* __restrict__ rowptr,
                                              const int2* __restrict__ cv, int N) {
    constexpr int Q = C / 4;
    int idx = blockIdx.x * 256 + threadIdx.x;
    int node = idx / Q, q = idx % Q;
    if (node >= N) return;
    int beg = rowptr[node], end = rowptr[node + 1];
    float ax = 0.f, ay = 0.f, az = 0.f, aw = 0.f;
    #pragma unroll 2
    for (int j = beg; j < end; ++j) {
        int2 p = cv[j];
        float nv = __int_as_float(p.y);
        float4 xv = *(const float4*)(xin + (size_t)p.x * C + q * 4);
        ax += nv * xv.x; ay += nv * xv.y; az += nv * xv.z; aw += nv * xv.w;
    }
    size_t off = (size_t)node * C + q * 4;
    float4 r;
    if (beta != 0.f) {
        float4 pv = *(const float4*)(xprev + off);
        r.x = alpha * ax + beta * pv.x;
        r.y = alpha * ay + beta * pv.y;
        r.z = alpha * az + beta * pv.z;
        r.w = alpha * aw + beta * pv.w;
    } else {
        r.x = alpha * ax; r.y = alpha * ay; r.z = alpha * az; r.w = alpha * aw;
    }
    *(float4*)(outp + off) = r;
}

// ---------------- fused gate GEMM + LSTM pointwise (register-blocked) --------
// 64 nodes/block, 256 threads = 16 output-groups x 16 node-groups.
// Thread tile: 4 nodes x 8 outputs. Output axis PERMUTED to o' = h*4+g so each
// thread owns all 4 gates of (node, h0), (node, h0+1) -> pointwise LSTM is
// register-local (no LDS gate stage, no extra barriers).
// Ws swizzled (pos = o' + 4*(o'>>5), stride 140) -> 2-way quad access (free).
// Ts reads: 16 contiguous float4 addresses -> 2-way (free); stride 68 de-banks
// the column-staging writes.
#define NB   64
#define WSLD 140
#define TSLD 68

__global__ void __launch_bounds__(256) k_step(
    const float* __restrict__ xb,    // [N][64]
    const float* __restrict__ TXB,   // [4][N][64]  x Cheb terms k=1..4
    float* __restrict__ THall,       // [5][N][32]  slice 0 = H (in/out), 1..4 terms
    float* __restrict__ Cst,         // [N][32]
    const float* __restrict__ Wx,    // [4][5][8][32]
    const float* __restrict__ Wh,    // [4][5][32][32]
    const float* __restrict__ w_c,   // [3][32]
    const float* __restrict__ bg,    // [4][32]
    int t, int N) {
    __shared__ float Ws[40 * WSLD];  // 22400 B
    __shared__ float Ts[40 * TSLD];  // 10880 B
    int tid = threadIdx.x;
    int base = blockIdx.x * NB;
    int og = tid & 15;
    int o0 = og * 8;                 // o' tile start (h0 = og*2, all 4 gates)
    int h0 = og * 2;
    int n0 = (tid >> 4) * 4;         // local node tile start
    int wp0 = o0 + 4 * (o0 >> 5);    // swizzled Ws position

    float acc[4][8];
    #pragma unroll
    for (int oj = 0; oj < 8; ++oj) {
        float b = bg[(oj & 3) * 32 + h0 + (oj >> 2)];
        #pragma unroll
        for (int nj = 0; nj < 4; ++nj) acc[nj][oj] = b;
    }

    // ---- chunk 0: x-terms (40 rows = 5 k x 8 ch) ----
    for (int i = tid; i < 40 * 128; i += 256) {
        int ci = i >> 7, o = i & 127;            // o = o' = h*4+g
        int k = ci >> 3, c = ci & 7, h = o >> 2, g = o & 3;
        Ws[ci * WSLD + o + 4 * (o >> 5)] = Wx[(((g * KCH + k) * 8) + c) * 32 + h];
    }
    for (int i = tid; i < NB * 10; i += 256) {
        int nl = i / 10, w = i % 10;
        int node = base + nl; if (node >= N) node = N - 1;
        int k = w >> 1, cc0 = (w & 1) * 4;
        const float* sp = (k == 0) ? (xb + (size_t)node * 64 + t * 8 + cc0)
                                   : (TXB + ((size_t)(k - 1) * N + node) * 64 + t * 8 + cc0);
        float4 v = *(const float4*)sp;
        int row = k * 8 + cc0;
        Ts[(row + 0) * TSLD + nl] = v.x;
        Ts[(row + 1) * TSLD + nl] = v.y;
        Ts[(row + 2) * TSLD + nl] = v.z;
        Ts[(row + 3) * TSLD + nl] = v.w;
    }
    __syncthreads();
    #pragma unroll 4
    for (int c = 0; c < 40; ++c) {
        float4 wA = *(const float4*)(Ws + c * WSLD + wp0);
        float4 wB = *(const float4*)(Ws + c * WSLD + wp0 + 4);
        float4 tA = *(const float4*)(Ts + c * TSLD + n0);
        float wv[8] = {wA.x, wA.y, wA.z, wA.w, wB.x, wB.y, wB.z, wB.w};
        float tv[4] = {tA.x, tA.y, tA.z, tA.w};
        #pragma unroll
        for (int nj = 0; nj < 4; ++nj)
            #pragma unroll
            for (int oj = 0; oj < 8; ++oj)
                acc[nj][oj] += tv[nj] * wv[oj];
    }

    // ---- chunks 1..5: H-terms k=0..4 (32 rows each) ----
    for (int k = 0; k < KCH; ++k) {
        __syncthreads();
        for (int i = tid; i < 32 * 128; i += 256) {
            int ci = i >> 7, o = i & 127;
            int h = o >> 2, g = o & 3;
            Ws[ci * WSLD + o + 4 * (o >> 5)] = Wh[(((g * KCH + k) * 32) + ci) * 32 + h];
        }
        for (int i = tid; i < NB * 8; i += 256) {
            int nl = i >> 3, q = i & 7;
            int node = base + nl; if (node >= N) node = N - 1;
            float4 v = *(const float4*)(THall + ((size_t)k * N + node) * 32 + q * 4);
            int row = q * 4;
            Ts[(row + 0) * TSLD + nl] = v.x;
            Ts[(row + 1) * TSLD + nl] = v.y;
            Ts[(row + 2) * TSLD + nl] = v.z;
            Ts[(row + 3) * TSLD + nl] = v.w;
        }
        __syncthreads();
        #pragma unroll 4
        for (int c = 0; c < 32; ++c) {
            float4 wA = *(const float4*)(Ws + c * WSLD + wp0);
            float4 wB = *(const float4*)(Ws + c * WSLD + wp0 + 4);
            float4 tA = *(const float4*)(Ts + c * TSLD + n0);
            float wv[8] = {wA.x, wA.y, wA.z, wA.w, wB.x, wB.y, wB.z, wB.w};
            float tv[4] = {tA.x, tA.y, tA.z, tA.w};
            #pragma unroll
            for (int nj = 0; nj < 4; ++nj)
                #pragma unroll
                for (int oj = 0; oj < 8; ++oj)
                    acc[nj][oj] += tv[nj] * wv[oj];
        }
    }

    // ---- LSTM pointwise, register-local ----
    float wci0 = w_c[h0],      wci1 = w_c[h0 + 1];
    float wcf0 = w_c[32 + h0], wcf1 = w_c[32 + h0 + 1];
    float wco0 = w_c[64 + h0], wco1 = w_c[64 + h0 + 1];
    #pragma unroll
    for (int nj = 0; nj < 4; ++nj) {
        int node = base + n0 + nj;
        if (node < N) {
            size_t idx = (size_t)node * 32 + h0;
            float2 Co = *(const float2*)(Cst + idx);
            float2 Cn2, Hn;
            {
                float I  = sigmoidf_(acc[nj][0] + wci0 * Co.x);
                float F  = sigmoidf_(acc[nj][1] + wcf0 * Co.x);
                float Tg = tanhf_(acc[nj][2]);
                float Cn = F * Co.x + I * Tg;
                float O  = sigmoidf_(acc[nj][3] + wco0 * Cn);
                Cn2.x = Cn; Hn.x = O * tanhf_(Cn);
            }
            {
                float I  = sigmoidf_(acc[nj][4] + wci1 * Co.y);
                float F  = sigmoidf_(acc[nj][5] + wcf1 * Co.y);
                float Tg = tanhf_(acc[nj][6]);
                float Cn = F * Co.y + I * Tg;
                float O  = sigmoidf_(acc[nj][7] + wco1 * Cn);
                Cn2.y = Cn; Hn.y = O * tanhf_(Cn);
            }
            *(float2*)(Cst + idx) = Cn2;
            *(float2*)(THall + idx) = Hn;     // slice 0 = new H
        }
    }
}

// out[n][p] = sum_h relu(H[n][h]) * W_lin[p][h] + b_lin[p]
__global__ void k_out(const float* __restrict__ H, const float* __restrict__ W_lin,
                      const float* __restrict__ b_lin, float* __restrict__ out, int N) {
    int idx = blockIdx.x * blockDim.x + threadIdx.x;
    if (idx >= N * PERIODS) return;
    int n = idx / PERIODS, p = idx % PERIODS;
    float acc = b_lin[p];
    #pragma unroll
    for (int h = 0; h < HID; ++h)
        acc += fmaxf(H[(size_t)n * HID + h], 0.f) * W_lin[p * HID + h];
    out[idx] = acc;
}

// ---------------- launch ----------------

extern "C" void kernel_launch(void* const* d_in, const int* in_sizes, int n_in,
                              void* d_out, int out_size, void* d_ws, size_t ws_size,
                              hipStream_t stream) {
    const float* xall  = (const float*)d_in[0];
    const int*   ei    = (const int*)d_in[1];
    const float* Wx    = (const float*)d_in[2];
    const float* Wh    = (const float*)d_in[3];
    const float* w_c   = (const float*)d_in[4];
    const float* bg    = (const float*)d_in[5];
    const float* W_lin = (const float*)d_in[6];
    const float* b_lin = (const float*)d_in[7];
    float* out = (float*)d_out;

    const int E = in_sizes[1] / 2;
    const int N = in_sizes[0] / (T_STEPS * F_IN);
    const int* src = ei;
    const int* dst = ei + E;

    char* p = (char*)d_ws;
    auto carve = [&](size_t bytes) -> void* {
        void* r = (void*)p;
        p += (bytes + 255) & ~(size_t)255;
        return r;
    };
    // zero block: degi, cnt, fill, Cst, THall slice 0 (= H0)
    char* zero_begin = p;
    int*   degi = (int*)  carve((size_t)N * 4);
    int*   cnt  = (int*)  carve((size_t)N * 4);
    int*   fill = (int*)  carve((size_t)N * 4);
    float* Cst  = (float*)carve((size_t)N * HID * 4);
    float* THall = (float*)carve((size_t)KCH * N * HID * 4);
    size_t zero_bytes = (size_t)((char*)THall - zero_begin) + (size_t)N * HID * 4;
    float* dis    = (float*)carve((size_t)N * 4);
    int*   rowptr = (int*)  carve((size_t)(N + 1) * 4);
    int2*  cv     = (int2*) carve((size_t)E * 8);
    float* xb     = (float*)carve((size_t)N * 64 * 4);        // [N][T*8]
    float* TXB    = (float*)carve((size_t)4 * N * 64 * 4);    // x Cheb terms k=1..4

    hipMemsetAsync(zero_begin, 0, zero_bytes, stream);

    const int TB = 256;
    k_count<<<(E + TB - 1) / TB, TB, 0, stream>>>(src, dst, degi, cnt, E);
    k_dis<<<(N + TB - 1) / TB, TB, 0, stream>>>(degi, dis, N);
    k_scan<<<1, 1024, 0, stream>>>(cnt, rowptr, N);
    k_scatter<<<(E + TB - 1) / TB, TB, 0, stream>>>(src, dst, dis, rowptr, fill, cv, E);
    k_xt<<<(N * T_STEPS + TB - 1) / TB, TB, 0, stream>>>(xall, xb, N);

    // batched x-phase Chebyshev terms over all timesteps (C = 64)
    float* TXB0 = TXB;
    float* TXB1 = TXB + (size_t)N * 64;
    float* TXB2 = TXB + (size_t)2 * N * 64;
    float* TXB3 = TXB + (size_t)3 * N * 64;
    const int lapx_grid = (N * 16 + TB - 1) / TB;
    k_lap4<64><<<lapx_grid, TB, 0, stream>>>(TXB0, xb,   nullptr, 1.f,  0.f, rowptr, cv, N);
    k_lap4<64><<<lapx_grid, TB, 0, stream>>>(TXB1, TXB0, xb,      2.f, -1.f, rowptr, cv, N);
    k_lap4<64><<<lapx_grid, TB, 0, stream>>>(TXB2, TXB1, TXB0,    2.f, -1.f, rowptr, cv, N);
    k_lap4<64><<<lapx_grid, TB, 0, stream>>>(TXB3, TXB2, TXB1,    2.f, -1.f, rowptr, cv, N);

    const int laph_grid = (N * 8 + TB - 1) / TB;
    const int step_grid = (N + NB - 1) / NB;
    float* TH0 = THall;
    float* TH1 = THall + (size_t)N * HID;
    float* TH2 = THall + (size_t)2 * N * HID;
    float* TH3 = THall + (size_t)3 * N * HID;
    float* TH4 = THall + (size_t)4 * N * HID;

    for (int t = 0; t < T_STEPS; ++t) {
        k_lap4<HID><<<laph_grid, TB, 0, stream>>>(TH1, TH0, nullptr, 1.f,  0.f, rowptr, cv, N);
        k_lap4<HID><<<laph_grid, TB, 0, stream>>>(TH2, TH1, TH0,     2.f, -1.f, rowptr, cv, N);
        k_lap4<HID><<<laph_grid, TB, 0, stream>>>(TH3, TH2, TH1,     2.f, -1.f, rowptr, cv, N);
        k_lap4<HID><<<laph_grid, TB, 0, stream>>>(TH4, TH3, TH2,     2.f, -1.f, rowptr, cv, N);
        k_step<<<step_grid, TB, 0, stream>>>(xb, TXB, THall, Cst, Wx, Wh, w_c, bg, t, N);
    }

    k_out<<<(N * PERIODS + TB - 1) / TB, TB, 0, stream>>>(TH0, W_lin, b_lin, out, N);
}